// Round 5
// baseline (48.764 us; speedup 1.0000x reference)
//
#include <hip/hip_runtime.h>
#include <stdint.h>

#define EPS 1e-6f
constexpr int B = 16, C = 26, H = 256, W = 256;
constexpr int CHW  = C * H * W;   // 1,703,936
constexpr int CHW4 = CHW / 4;     // 425,984 float4s per batch
constexpr int HW2  = 2 * H * W;   // 131,072
constexpr int P = 20, K = 2, E = 26;
constexpr int NBPB = 64;          // focal blocks per batch -> 1024 blocks = 4/CU
constexpr int NT = 26;            // tiles per block
constexpr int TILE = 256;         // float4s per tile per stream
constexpr int CHUNK = NT * TILE;  // 6656 float4s per stream per block
static_assert(NBPB * CHUNK == CHW4, "exact tiling");
constexpr int DEPTH = 4;          // LDS buffers per wave (pipeline depth 3 ahead)

typedef float f32x4 __attribute__((ext_vector_type(4)));

__device__ __forceinline__ void gload_lds16(const f32x4* g, f32x4* l) {
  __builtin_amdgcn_global_load_lds(
      (const __attribute__((address_space(1))) uint32_t*)g,
      (__attribute__((address_space(3))) uint32_t*)l, 16, 0, 0);
}

__device__ inline float waveReduceSum(float v) {
#pragma unroll
  for (int o = 32; o > 0; o >>= 1) v += __shfl_down(v, o, 64);
  return v;
}

__device__ inline float halfReduceSum(float v) {  // width-32 reduce
#pragma unroll
  for (int o = 16; o > 0; o >>= 1) v += __shfl_xor(v, o, 32);
  return v;
}

// ---------------- Kernel 1: focal-loss partial reduction ----------------
// grid (NBPB, B) x 256. Per-wave private LDS quad-buffer filled by
// global_load_lds DMA (no VGPR round-trip, no barriers); counted vmcnt keeps
// 3 tiles (6 loads, 6 KB) in flight per wave at steady state.
__global__ __launch_bounds__(256) void focal_partial_kernel(
    const f32x4* __restrict__ pred, const f32x4* __restrict__ gt,
    float* __restrict__ partials) {
  __shared__ f32x4 lds[4][DEPTH][2][64];  // [wave][buf][stream][lane] = 32 KB
  const int b = blockIdx.y;
  const int w = threadIdx.x >> 6, lane = threadIdx.x & 63;
  const size_t base =
      (size_t)b * CHW4 + (size_t)blockIdx.x * CHUNK + w * 64 + lane;
  const f32x4* gP = pred + base;
  const f32x4* gG = gt + base;

  // prologue: issue tiles 0..DEPTH-2
#pragma unroll
  for (int t = 0; t < DEPTH - 1; ++t) {
    gload_lds16(gP + t * TILE, &lds[w][t][0][0]);
    gload_lds16(gG + t * TILE, &lds[w][t][1][0]);
  }

  float pl = 0.f, nl = 0.f, npos = 0.f;
  for (int it = 0; it < NT; ++it) {
    const int bf = it & (DEPTH - 1);
    if (it + DEPTH - 1 < NT) {
      const int tn = it + DEPTH - 1;
      gload_lds16(gP + tn * TILE, &lds[w][tn & (DEPTH - 1)][0][0]);
      gload_lds16(gG + tn * TILE, &lds[w][tn & (DEPTH - 1)][1][0]);
      asm volatile("s_waitcnt vmcnt(6)" ::: "memory");  // tile `it` landed
    } else if (it == NT - 3) {
      asm volatile("s_waitcnt vmcnt(4)" ::: "memory");
    } else if (it == NT - 2) {
      asm volatile("s_waitcnt vmcnt(2)" ::: "memory");
    } else {
      asm volatile("s_waitcnt vmcnt(0)" ::: "memory");
    }
    __builtin_amdgcn_sched_barrier(0);  // rule #18: pin reads after waitcnt

    f32x4 xc = lds[w][bf][0][lane];
    f32x4 gc = lds[w][bf][1][lane];
#pragma unroll
    for (int j = 0; j < 4; ++j) {
      float x = xc[j], g = gc[j];
      float p = __builtin_amdgcn_rcpf(1.f + __expf(-x));
      bool pos = (g == 1.0f);
      float og = 1.f - g;
      float og2 = og * og;
      float omp = 1.f - p;
      // neg weight (1-g)^4 is 0 at g==1, so one selected log serves both
      float arg = pos ? (p + EPS) : (1.f - p + EPS);
      float wt  = pos ? (omp * omp) : (p * p * (og2 * og2));
      float lw  = __logf(arg) * wt;
      pl   += pos ? lw : 0.f;
      nl   += pos ? 0.f : lw;
      npos += pos ? 1.f : 0.f;
    }
  }

  pl = waveReduceSum(pl);
  nl = waveReduceSum(nl);
  npos = waveReduceSum(npos);
  __shared__ float s[3][4];
  if (lane == 0) { s[0][w] = pl; s[1][w] = nl; s[2][w] = npos; }
  __syncthreads();
  if (threadIdx.x == 0) {
    float* o = partials + ((size_t)b * NBPB + blockIdx.x) * 4;
    o[0] = s[0][0] + s[0][1] + s[0][2] + s[0][3];
    o[1] = s[1][0] + s[1][1] + s[1][2] + s[1][3];
    o[2] = s[2][0] + s[2][1] + s[2][2] + s[2][3];
    o[3] = 0.f;
  }
}

// ---------------- Kernel 2: fused tail (hw + bu + finalize) ----------------
// grid (B) x 256. Phase A: reduce NBPB focal partials. Phase B (wave 0): hw
// L1 gather. Phase C: bu tag loss, 2 persons per wave via 32-lane halves.
__global__ __launch_bounds__(256) void tail_kernel(
    const float* __restrict__ partials,
    const float* __restrict__ hw_pred, const float* __restrict__ hw_gt,
    const float* __restrict__ bu_pred, const float* __restrict__ bu_gt,
    float* __restrict__ out) {
  const int b = blockIdx.x, t = threadIdx.x;
  const int wave = t >> 6, lane = t & 63;
  __shared__ float sA[3][4];
  __shared__ float sHW[2];
  __shared__ float sPP[P], sPV[P];

  // ---- Phase A: focal partial reduction (threads 0..NBPB-1 active) ----
  float pl = 0.f, nl = 0.f, np = 0.f;
  if (t < NBPB) {
    const float* o = partials + ((size_t)b * NBPB + t) * 4;
    pl = o[0]; nl = o[1]; np = o[2];
  }
  pl = waveReduceSum(pl);
  nl = waveReduceSum(nl);
  np = waveReduceSum(np);
  if (lane == 0) { sA[0][wave] = pl; sA[1][wave] = nl; sA[2][wave] = np; }

  // ---- Phase B: hw reg-L1 (wave 0, lanes 0..39) ----
  if (wave == 0) {
    float contrib = 0.f;
    bool wv = false;
    if (lane < P * K) {
      const float* g3 = hw_gt + ((size_t)(b * P * K + lane)) * 3;
      float val = g3[0];
      int idx = (int)g3[1];
      wv = g3[2] > 0.f;
      float gvv = hw_pred[(size_t)b * HW2 + idx];
      contrib = wv ? fabsf(gvv - val) : 0.f;
    }
    unsigned long long m = __ballot(wv);
    float l1 = waveReduceSum(contrib);
    if (lane == 0) {
      unsigned long long mm = (m | (m >> 1)) & 0x5555555555ULL;
      sHW[0] = l1;
      sHW[1] = (float)__popcll(mm);
    }
  }

  // ---- Phase C: bu tag loss, persons p = pbase + wave*2 + half ----
  const int half = lane >> 5, l = lane & 31;
  for (int pbase = 0; pbase < P; pbase += 8) {
    int p = pbase + wave * 2 + half;
    float plp = 0.f, nlp = 0.f, npp = 0.f;
    bool mv = false;
    if (p < P && l < E) {
      const float* g3 = bu_gt + ((size_t)((b * P + p) * E + l)) * 3;
      float val = g3[0];
      int idx = (int)g3[1];
      mv = g3[2] > 0.f;
      float x = bu_pred[(size_t)b * CHW + idx];
      float gv = __builtin_amdgcn_rcpf(1.f + __expf(-x));
      if (mv) {
        if (val == 1.0f) {
          float o = 1.f - gv;
          plp = __logf(gv + EPS) * o * o;
          npp = 1.f;
        } else {
          nlp = __logf(1.f - gv + EPS) * gv * gv;
        }
      }
    }
    plp = halfReduceSum(plp);
    nlp = halfReduceSum(nlp);
    npp = halfReduceSum(npp);
    unsigned long long m = __ballot(mv);
    bool any = half ? ((m >> 32) != 0ULL) : ((m & 0xffffffffULL) != 0ULL);
    if (l == 0 && p < P) {
      float per = (npp == 0.f) ? -nlp : -(plp + nlp);
      float pv = any ? 1.f : 0.f;
      sPP[p] = per * pv;
      sPV[p] = pv;
    }
  }

  __syncthreads();
  if (t == 0) {
    float PL = sA[0][0] + sA[0][1] + sA[0][2] + sA[0][3];
    float NL = sA[1][0] + sA[1][1] + sA[1][2] + sA[1][3];
    float NP = sA[2][0] + sA[2][1] + sA[2][2] + sA[2][3];
    float hm = (NP > 0.f) ? (-(PL + NL) / fmaxf(NP, 1.f)) : -NL;
    out[b] = hm * 1.0f;  // HM_FACTOR
    float l1 = sHW[0], npe = sHW[1];
    out[16 + b] = ((npe > 0.f) ? l1 / fmaxf(npe, 1.f) : 0.f) * 0.1f;  // HW_FACTOR
    float spp = 0.f, spv = 0.f;
#pragma unroll
    for (int i = 0; i < P; ++i) { spp += sPP[i]; spv += sPV[i]; }
    out[32 + b] = (spp / fmaxf(spv, 1.f)) * 1.0f;  // BU_FACTOR
  }
}

extern "C" void kernel_launch(void* const* d_in, const int* in_sizes, int n_in,
                              void* d_out, int out_size, void* d_ws, size_t ws_size,
                              hipStream_t stream) {
  const float* hm_pred = (const float*)d_in[0];
  const float* hm_gt   = (const float*)d_in[1];
  const float* hw_pred = (const float*)d_in[2];
  const float* hw_gt   = (const float*)d_in[3];
  const float* bu_pred = (const float*)d_in[4];
  const float* bu_gt   = (const float*)d_in[5];
  float* out = (float*)d_out;

  float* partials = (float*)d_ws;  // B*NBPB*4 = 4096 floats

  hipLaunchKernelGGL(focal_partial_kernel, dim3(NBPB, B), dim3(256), 0, stream,
                     (const f32x4*)hm_pred, (const f32x4*)hm_gt, partials);
  hipLaunchKernelGGL(tail_kernel, dim3(B), dim3(256), 0, stream,
                     partials, hw_pred, hw_gt, bu_pred, bu_gt, out);
}

// Round 6
// 46.327 us; speedup vs baseline: 1.0526x; 1.0526x over previous
//
#include <hip/hip_runtime.h>
#include <stdint.h>

#define EPS 1e-6f
constexpr int B = 16, C = 26, H = 256, W = 256;
constexpr int CHW  = C * H * W;   // 1,703,936
constexpr int CHW4 = CHW / 4;     // 425,984 float4s per batch
constexpr int HW2  = 2 * H * W;   // 131,072
constexpr int P = 20, K = 2, E = 26;
constexpr int NBPB = 128;         // focal blocks per batch -> 2048 blocks = 8/CU
constexpr int ITER = 13;          // float4-pair iterations per thread
constexpr int TILE = 256;         // float4s per iteration per stream (block-wide)
constexpr int CHUNK = ITER * TILE;  // 3328 float4s per stream per block
static_assert(NBPB * CHUNK == CHW4, "exact tiling");
constexpr int DEPTH = 4;          // pairs in flight ahead of compute

typedef float f32x4 __attribute__((ext_vector_type(4)));

__device__ inline float waveReduceSum(float v) {
#pragma unroll
  for (int o = 32; o > 0; o >>= 1) v += __shfl_down(v, o, 64);
  return v;
}

__device__ inline float halfReduceSum(float v) {  // width-32 reduce
#pragma unroll
  for (int o = 16; o > 0; o >>= 1) v += __shfl_xor(v, o, 32);
  return v;
}

// Volatile asm load: cannot be sunk/reordered by the compiler -> guaranteed
// issue order and guaranteed in-flight depth.
__device__ __forceinline__ void force_load(const f32x4* a, f32x4& d) {
  asm volatile("global_load_dwordx4 %0, %1, off" : "=v"(d) : "v"(a));
}

__device__ __forceinline__ void fma_elem(float x, float g, float& pl,
                                         float& nl, float& npos) {
  float p = __builtin_amdgcn_rcpf(1.f + __expf(-x));
  bool pos = (g == 1.0f);
  float og = 1.f - g;
  float og2 = og * og;
  float omp = 1.f - p;
  // neg weight (1-g)^4 is 0 at g==1, so one selected log serves both paths
  float arg = pos ? (p + EPS) : (1.f - p + EPS);
  float wt  = pos ? (omp * omp) : (p * p * (og2 * og2));
  float lw  = __logf(arg) * wt;
  pl   += pos ? lw : 0.f;
  nl   += pos ? 0.f : lw;
  npos += pos ? 1.f : 0.f;
}

template <int IT>
__device__ __forceinline__ void step(const f32x4* gP, const f32x4* gG,
                                     f32x4 (&bx)[ITER], f32x4 (&bg)[ITER],
                                     float& pl, float& nl, float& npos) {
  if constexpr (IT < ITER) {
    // issue pair IT+DEPTH (keeps DEPTH pairs ahead)
    if constexpr (IT + DEPTH < ITER) {
      force_load(gP + (IT + DEPTH) * TILE, bx[IT + DEPTH]);
      force_load(gG + (IT + DEPTH) * TILE, bg[IT + DEPTH]);
    }
    // wait until pair IT has landed: allowed = 2*(min(IT+DEPTH,ITER-1)-IT)
    constexpr int rem =
        2 * ((IT + DEPTH < ITER ? IT + DEPTH : ITER - 1) - IT);
    if constexpr (rem >= 8)      asm volatile("s_waitcnt vmcnt(8)" ::: "memory");
    else if constexpr (rem == 6) asm volatile("s_waitcnt vmcnt(6)" ::: "memory");
    else if constexpr (rem == 4) asm volatile("s_waitcnt vmcnt(4)" ::: "memory");
    else if constexpr (rem == 2) asm volatile("s_waitcnt vmcnt(2)" ::: "memory");
    else                         asm volatile("s_waitcnt vmcnt(0)" ::: "memory");
    // tie the values through the wait so compute can't be hoisted above it
    asm volatile("" : "+v"(bx[IT]), "+v"(bg[IT]));
    __builtin_amdgcn_sched_barrier(0);
#pragma unroll
    for (int j = 0; j < 4; ++j) fma_elem(bx[IT][j], bg[IT][j], pl, nl, npos);
    step<IT + 1>(gP, gG, bx, bg, pl, nl, npos);
  }
}

// ---------------- Kernel 1: focal-loss partial reduction ----------------
// grid (NBPB, B) x 256. Contiguous 52 KB chunk per block per stream; forced
// depth-4-pair (8 KB/wave) global->VGPR pipeline with counted vmcnt.
__global__ __launch_bounds__(256, 8) void focal_partial_kernel(
    const f32x4* __restrict__ pred, const f32x4* __restrict__ gt,
    float* __restrict__ partials) {
  const int b = blockIdx.y;
  const size_t base =
      (size_t)b * CHW4 + (size_t)blockIdx.x * CHUNK + threadIdx.x;
  const f32x4* gP = pred + base;
  const f32x4* gG = gt + base;

  f32x4 bx[ITER], bg[ITER];
  // prologue: pairs 0..DEPTH-1
#pragma unroll
  for (int t = 0; t < DEPTH; ++t) {
    force_load(gP + t * TILE, bx[t]);
    force_load(gG + t * TILE, bg[t]);
  }

  float pl = 0.f, nl = 0.f, npos = 0.f;
  step<0>(gP, gG, bx, bg, pl, nl, npos);

  pl = waveReduceSum(pl);
  nl = waveReduceSum(nl);
  npos = waveReduceSum(npos);
  __shared__ float s[3][4];
  int wave = threadIdx.x >> 6, lane = threadIdx.x & 63;
  if (lane == 0) { s[0][wave] = pl; s[1][wave] = nl; s[2][wave] = npos; }
  __syncthreads();
  if (threadIdx.x == 0) {
    float* o = partials + ((size_t)b * NBPB + blockIdx.x) * 4;
    o[0] = s[0][0] + s[0][1] + s[0][2] + s[0][3];
    o[1] = s[1][0] + s[1][1] + s[1][2] + s[1][3];
    o[2] = s[2][0] + s[2][1] + s[2][2] + s[2][3];
    o[3] = 0.f;
  }
}

// ---------------- Kernel 2: fused tail (hw + bu + finalize) ----------------
__global__ __launch_bounds__(256) void tail_kernel(
    const float* __restrict__ partials,
    const float* __restrict__ hw_pred, const float* __restrict__ hw_gt,
    const float* __restrict__ bu_pred, const float* __restrict__ bu_gt,
    float* __restrict__ out) {
  const int b = blockIdx.x, t = threadIdx.x;
  const int wave = t >> 6, lane = t & 63;
  __shared__ float sA[3][4];
  __shared__ float sHW[2];
  __shared__ float sPP[P], sPV[P];

  // ---- Phase A: focal partial reduction (threads 0..NBPB-1 active) ----
  float pl = 0.f, nl = 0.f, np = 0.f;
  if (t < NBPB) {
    const float* o = partials + ((size_t)b * NBPB + t) * 4;
    pl = o[0]; nl = o[1]; np = o[2];
  }
  pl = waveReduceSum(pl);
  nl = waveReduceSum(nl);
  np = waveReduceSum(np);
  if (lane == 0) { sA[0][wave] = pl; sA[1][wave] = nl; sA[2][wave] = np; }

  // ---- Phase B: hw reg-L1 (wave 0, lanes 0..39) ----
  if (wave == 0) {
    float contrib = 0.f;
    bool wv = false;
    if (lane < P * K) {
      const float* g3 = hw_gt + ((size_t)(b * P * K + lane)) * 3;
      float val = g3[0];
      int idx = (int)g3[1];
      wv = g3[2] > 0.f;
      float gvv = hw_pred[(size_t)b * HW2 + idx];
      contrib = wv ? fabsf(gvv - val) : 0.f;
    }
    unsigned long long m = __ballot(wv);
    float l1 = waveReduceSum(contrib);
    if (lane == 0) {
      unsigned long long mm = (m | (m >> 1)) & 0x5555555555ULL;
      sHW[0] = l1;
      sHW[1] = (float)__popcll(mm);
    }
  }

  // ---- Phase C: bu tag loss, persons p = pbase + wave*2 + half ----
  const int half = lane >> 5, l = lane & 31;
  for (int pbase = 0; pbase < P; pbase += 8) {
    int p = pbase + wave * 2 + half;
    float plp = 0.f, nlp = 0.f, npp = 0.f;
    bool mv = false;
    if (p < P && l < E) {
      const float* g3 = bu_gt + ((size_t)((b * P + p) * E + l)) * 3;
      float val = g3[0];
      int idx = (int)g3[1];
      mv = g3[2] > 0.f;
      float x = bu_pred[(size_t)b * CHW + idx];
      float gv = __builtin_amdgcn_rcpf(1.f + __expf(-x));
      if (mv) {
        if (val == 1.0f) {
          float o = 1.f - gv;
          plp = __logf(gv + EPS) * o * o;
          npp = 1.f;
        } else {
          nlp = __logf(1.f - gv + EPS) * gv * gv;
        }
      }
    }
    plp = halfReduceSum(plp);
    nlp = halfReduceSum(nlp);
    npp = halfReduceSum(npp);
    unsigned long long m = __ballot(mv);
    bool any = half ? ((m >> 32) != 0ULL) : ((m & 0xffffffffULL) != 0ULL);
    if (l == 0 && p < P) {
      float per = (npp == 0.f) ? -nlp : -(plp + nlp);
      float pv = any ? 1.f : 0.f;
      sPP[p] = per * pv;
      sPV[p] = pv;
    }
  }

  __syncthreads();
  if (t == 0) {
    float PL = sA[0][0] + sA[0][1] + sA[0][2] + sA[0][3];
    float NL = sA[1][0] + sA[1][1] + sA[1][2] + sA[1][3];
    float NP = sA[2][0] + sA[2][1] + sA[2][2] + sA[2][3];
    float hm = (NP > 0.f) ? (-(PL + NL) / fmaxf(NP, 1.f)) : -NL;
    out[b] = hm * 1.0f;  // HM_FACTOR
    float l1 = sHW[0], npe = sHW[1];
    out[16 + b] = ((npe > 0.f) ? l1 / fmaxf(npe, 1.f) : 0.f) * 0.1f;  // HW_FACTOR
    float spp = 0.f, spv = 0.f;
#pragma unroll
    for (int i = 0; i < P; ++i) { spp += sPP[i]; spv += sPV[i]; }
    out[32 + b] = (spp / fmaxf(spv, 1.f)) * 1.0f;  // BU_FACTOR
  }
}

extern "C" void kernel_launch(void* const* d_in, const int* in_sizes, int n_in,
                              void* d_out, int out_size, void* d_ws, size_t ws_size,
                              hipStream_t stream) {
  const float* hm_pred = (const float*)d_in[0];
  const float* hm_gt   = (const float*)d_in[1];
  const float* hw_pred = (const float*)d_in[2];
  const float* hw_gt   = (const float*)d_in[3];
  const float* bu_pred = (const float*)d_in[4];
  const float* bu_gt   = (const float*)d_in[5];
  float* out = (float*)d_out;

  float* partials = (float*)d_ws;  // B*NBPB*4 = 8192 floats

  hipLaunchKernelGGL(focal_partial_kernel, dim3(NBPB, B), dim3(256), 0, stream,
                     (const f32x4*)hm_pred, (const f32x4*)hm_gt, partials);
  hipLaunchKernelGGL(tail_kernel, dim3(B), dim3(256), 0, stream,
                     partials, hw_pred, hw_gt, bu_pred, bu_gt, out);
}

// Round 7
// 43.854 us; speedup vs baseline: 1.1120x; 1.0564x over previous
//
#include <hip/hip_runtime.h>
#include <stdint.h>

#define EPS 1e-6f
constexpr int B = 16, C = 26, H = 256, W = 256;
constexpr int CHW  = C * H * W;   // 1,703,936
constexpr int CHW4 = CHW / 4;     // 425,984 float4s per batch
constexpr int HW2  = 2 * H * W;   // 131,072
constexpr int P = 20, K = 2, E = 26;
constexpr int NBPB = 128;         // focal blocks per batch
constexpr int ITER = 13;          // per-thread float4 iterations
constexpr int CHUNK = ITER * 256; // 3328 float4s per block per stream
static_assert(NBPB * CHUNK == CHW4, "exact tiling");

typedef float f32x4 __attribute__((ext_vector_type(4)));

__device__ inline float waveReduceSum(float v) {
#pragma unroll
  for (int o = 32; o > 0; o >>= 1) v += __shfl_down(v, o, 64);
  return v;
}

__device__ inline float halfReduceSum(float v) {  // width-32 reduce
#pragma unroll
  for (int o = 16; o > 0; o >>= 1) v += __shfl_xor(v, o, 32);
  return v;
}

// ---------------- Kernel 1: focal partials + aux (hw/bu) block ----------------
// grid (NBPB+1, B) x 256. Blocks 0..NBPB-1: contiguous-chunk focal reduction
// (round-4 structure: compiler-scheduled depth-2 rotation, VGPR~20, best
// measured). Block NBPB: hw L1 gather (wave 0) + bu tag gathers (all waves),
// overlapped under focal's 40 us instead of serialized after it.
__global__ __launch_bounds__(256) void focal_partial_kernel(
    const f32x4* __restrict__ pred, const f32x4* __restrict__ gt,
    const float* __restrict__ hw_pred, const float* __restrict__ hw_gt,
    const float* __restrict__ bu_pred, const float* __restrict__ bu_gt,
    float* __restrict__ ws) {
  const int b = blockIdx.y;
  float* partials = ws;                      // [B][NBPB][4]
  float* hw_res   = ws + B * NBPB * 4;       // [B][2]
  float* bu_pp    = hw_res + B * 2;          // [B][P]
  float* bu_pv    = bu_pp + B * P;           // [B][P]

  if (blockIdx.x == NBPB) {
    // ---------------- aux block: hw + bu for batch b ----------------
    const int t = threadIdx.x, wave = t >> 6, lane = t & 63;
    if (wave == 0) {
      float contrib = 0.f;
      bool wv = false;
      if (lane < P * K) {
        const float* g3 = hw_gt + ((size_t)(b * P * K + lane)) * 3;
        float val = g3[0];
        int idx = (int)g3[1];
        wv = g3[2] > 0.f;
        float gvv = hw_pred[(size_t)b * HW2 + idx];
        contrib = wv ? fabsf(gvv - val) : 0.f;
      }
      unsigned long long m = __ballot(wv);
      float l1 = waveReduceSum(contrib);
      if (lane == 0) {
        unsigned long long mm = (m | (m >> 1)) & 0x5555555555ULL;
        hw_res[b * 2 + 0] = l1;
        hw_res[b * 2 + 1] = (float)__popcll(mm);
      }
    }
    const int half = lane >> 5, l = lane & 31;
#pragma unroll
    for (int pbase = 0; pbase < P; pbase += 8) {
      int p = pbase + wave * 2 + half;
      float plp = 0.f, nlp = 0.f, npp = 0.f;
      bool mv = false;
      if (p < P && l < E) {
        const float* g3 = bu_gt + ((size_t)((b * P + p) * E + l)) * 3;
        float val = g3[0];
        int idx = (int)g3[1];
        mv = g3[2] > 0.f;
        float x = bu_pred[(size_t)b * CHW + idx];
        float gv = __builtin_amdgcn_rcpf(1.f + __expf(-x));
        if (mv) {
          if (val == 1.0f) {
            float o = 1.f - gv;
            plp = __logf(gv + EPS) * o * o;
            npp = 1.f;
          } else {
            nlp = __logf(1.f - gv + EPS) * gv * gv;
          }
        }
      }
      plp = halfReduceSum(plp);
      nlp = halfReduceSum(nlp);
      npp = halfReduceSum(npp);
      unsigned long long m = __ballot(mv);
      bool any = half ? ((m >> 32) != 0ULL) : ((m & 0xffffffffULL) != 0ULL);
      if (l == 0 && p < P) {
        float per = (npp == 0.f) ? -nlp : -(plp + nlp);
        float pv = any ? 1.f : 0.f;
        bu_pp[b * P + p] = per * pv;
        bu_pv[b * P + p] = pv;
      }
    }
    return;
  }

  // ---------------- focal block ----------------
  const size_t base = (size_t)b * CHW4 + (size_t)blockIdx.x * CHUNK;
  const f32x4* pp = pred + base;
  const f32x4* gg = gt + base;
  const int tid = threadIdx.x;

  f32x4 xc = pp[tid];
  f32x4 gc = gg[tid];

  float pl = 0.f, nl = 0.f, npos = 0.f;
#pragma unroll
  for (int it = 0; it < ITER; ++it) {
    f32x4 xn, gn;
    if (it + 1 < ITER) {
      xn = pp[(it + 1) * 256 + tid];
      gn = gg[(it + 1) * 256 + tid];
    }
#pragma unroll
    for (int j = 0; j < 4; ++j) {
      float x = xc[j], g = gc[j];
      float p = __builtin_amdgcn_rcpf(1.f + __expf(-x));
      bool pos = (g == 1.0f);
      float og = 1.f - g;
      float og2 = og * og;
      float omp = 1.f - p;
      // neg weight (1-g)^4 is 0 at g==1, so one selected log serves both
      float arg = pos ? (p + EPS) : (1.f - p + EPS);
      float wt  = pos ? (omp * omp) : (p * p * (og2 * og2));
      float lw  = __logf(arg) * wt;
      pl   += pos ? lw : 0.f;
      nl   += pos ? 0.f : lw;
      npos += pos ? 1.f : 0.f;
    }
    if (it + 1 < ITER) { xc = xn; gc = gn; }
  }

  pl = waveReduceSum(pl);
  nl = waveReduceSum(nl);
  npos = waveReduceSum(npos);
  __shared__ float s[3][4];
  int wave = threadIdx.x >> 6, lane = threadIdx.x & 63;
  if (lane == 0) { s[0][wave] = pl; s[1][wave] = nl; s[2][wave] = npos; }
  __syncthreads();
  if (threadIdx.x == 0) {
    float* o = partials + ((size_t)b * NBPB + blockIdx.x) * 4;
    o[0] = s[0][0] + s[0][1] + s[0][2] + s[0][3];
    o[1] = s[1][0] + s[1][1] + s[1][2] + s[1][3];
    o[2] = s[2][0] + s[2][1] + s[2][2] + s[2][3];
    o[3] = 0.f;
  }
}

// ---------------- Kernel 2: slim finalize ----------------
// grid (B) x 256. Waves 0-1: reduce NBPB focal partials. Wave 2: bu sums
// (parallel lane reads). Wave 3: hw scalars. Thread 0 combines.
__global__ __launch_bounds__(256) void tail_kernel(
    const float* __restrict__ ws, float* __restrict__ out) {
  const int b = blockIdx.x, t = threadIdx.x;
  const int wave = t >> 6, lane = t & 63;
  const float* partials = ws;
  const float* hw_res   = ws + B * NBPB * 4;
  const float* bu_pp    = hw_res + B * 2;
  const float* bu_pv    = bu_pp + B * P;

  __shared__ float sA[3][2];
  __shared__ float sBU[2];
  __shared__ float sHW[2];

  if (wave < 2) {  // phase A: 128 partials
    const float* o = partials + ((size_t)b * NBPB + t) * 4;
    float pl = o[0], nl = o[1], np = o[2];
    pl = waveReduceSum(pl);
    nl = waveReduceSum(nl);
    np = waveReduceSum(np);
    if (lane == 0) { sA[0][wave] = pl; sA[1][wave] = nl; sA[2][wave] = np; }
  } else if (wave == 2) {  // bu sums
    float pp = (lane < P) ? bu_pp[b * P + lane] : 0.f;
    float pv = (lane < P) ? bu_pv[b * P + lane] : 0.f;
    pp = waveReduceSum(pp);
    pv = waveReduceSum(pv);
    if (lane == 0) { sBU[0] = pp; sBU[1] = pv; }
  } else {  // hw scalars
    float v = (lane < 2) ? hw_res[b * 2 + lane] : 0.f;
    if (lane < 2) sHW[lane] = v;
  }
  __syncthreads();
  if (t == 0) {
    float PL = sA[0][0] + sA[0][1];
    float NL = sA[1][0] + sA[1][1];
    float NP = sA[2][0] + sA[2][1];
    float hm = (NP > 0.f) ? (-(PL + NL) / fmaxf(NP, 1.f)) : -NL;
    out[b] = hm * 1.0f;  // HM_FACTOR
    float l1 = sHW[0], npe = sHW[1];
    out[16 + b] = ((npe > 0.f) ? l1 / fmaxf(npe, 1.f) : 0.f) * 0.1f;  // HW_FACTOR
    out[32 + b] = (sBU[0] / fmaxf(sBU[1], 1.f)) * 1.0f;  // BU_FACTOR
  }
}

extern "C" void kernel_launch(void* const* d_in, const int* in_sizes, int n_in,
                              void* d_out, int out_size, void* d_ws, size_t ws_size,
                              hipStream_t stream) {
  const float* hm_pred = (const float*)d_in[0];
  const float* hm_gt   = (const float*)d_in[1];
  const float* hw_pred = (const float*)d_in[2];
  const float* hw_gt   = (const float*)d_in[3];
  const float* bu_pred = (const float*)d_in[4];
  const float* bu_gt   = (const float*)d_in[5];
  float* out = (float*)d_out;
  float* ws = (float*)d_ws;  // partials + hw_res + bu_pp + bu_pv

  hipLaunchKernelGGL(focal_partial_kernel, dim3(NBPB + 1, B), dim3(256), 0,
                     stream, (const f32x4*)hm_pred, (const f32x4*)hm_gt,
                     hw_pred, hw_gt, bu_pred, bu_gt, ws);
  hipLaunchKernelGGL(tail_kernel, dim3(B), dim3(256), 0, stream, ws, out);
}